// Round 1
// baseline (3396.489 us; speedup 1.0000x reference)
//
#include <hip/hip_runtime.h>
#include <math.h>

// SimpleTTTRouter: logits = x @ W^T + b ; softmax ; top-2 ; renormalize.
// x: [16384, 4096] f32, W: [128, 4096] f32, b: [128] f32.
// out: [16384*2] indices (as float) ++ [16384*2] probs (float), 65536 floats.
//
// Design: fp32 VALU GEMV-batch. lane = token, so W[e][k] is wave-uniform ->
// scalar loads (s_load) feed v_fma_f32 with an SGPR operand; x streams via
// VMEM per-lane; acc[128] lives in VGPRs. 8-way K-split across the block's
// 8 waves (2 waves/SIMD), LDS atomic reduction, fused softmax/top-2 epilogue.

#define T_TOKENS 16384
#define D_K      4096
#define N_EXP    128
#define SPLITK   8
#define TOK_PER_BLOCK 64
#define KSLICE   (D_K / SPLITK)   // 512
#define KCHUNK   4

__global__ __launch_bounds__(64 * SPLITK, 2)
void router_kernel(const float* __restrict__ x,
                   const float* __restrict__ W,
                   const float* __restrict__ b,
                   float* __restrict__ out) {
    __shared__ float red[N_EXP * TOK_PER_BLOCK];   // [expert][token] 32 KB

    const int lane = threadIdx.x & 63;
    // readfirstlane forces wave-uniformity so W addressing becomes SMEM.
    const int wave = __builtin_amdgcn_readfirstlane(threadIdx.x >> 6);
    const int tok  = blockIdx.x * TOK_PER_BLOCK + lane;

    // zero the reduction buffer (barrier below covers this: every thread's
    // atomics happen only after ALL threads passed zeroing + K-loop)
    for (int i = threadIdx.x; i < N_EXP * TOK_PER_BLOCK; i += blockDim.x)
        red[i] = 0.0f;

    float acc[N_EXP];
#pragma unroll
    for (int e = 0; e < N_EXP; ++e) acc[e] = 0.0f;

    const float* xrow = x + (size_t)tok * D_K;
    const int k_begin = wave * KSLICE;

    for (int k0 = k_begin; k0 < k_begin + KSLICE; k0 += KCHUNK) {
        const float4 xv = *(const float4*)(xrow + k0);   // per-lane VMEM
        const float* wp = W + k0;                        // wave-uniform
#pragma unroll
        for (int e = 0; e < N_EXP; ++e) {
            const float4 wv = *(const float4*)(wp + (size_t)e * D_K); // s_load
            acc[e] = fmaf(xv.x, wv.x, acc[e]);
            acc[e] = fmaf(xv.y, wv.y, acc[e]);
            acc[e] = fmaf(xv.z, wv.z, acc[e]);
            acc[e] = fmaf(xv.w, wv.w, acc[e]);
        }
    }

    __syncthreads();   // all zeroing + all K-loops complete

    // 8-way cross-wave reduction; [e][lane] layout is lane-contiguous
    // (conflict-free; 2 lanes/bank aliasing is free on gfx950).
#pragma unroll 8
    for (int e = 0; e < N_EXP; ++e)
        atomicAdd(&red[e * TOK_PER_BLOCK + lane], acc[e]);

    __syncthreads();

    if (wave == 0) {
        // lane t handles token tok: top-2 scan (jax top_k tie-break: first
        // occurrence wins via strict >), then softmax Z, then renormalize.
        float v1 = -INFINITY, v2 = -INFINITY;
        int   i1 = 0, i2 = 0;
        for (int e = 0; e < N_EXP; ++e) {
            const float l = red[e * TOK_PER_BLOCK + lane] + b[e];
            if (l > v1)      { v2 = v1; i2 = i1; v1 = l; i1 = e; }
            else if (l > v2) { v2 = l; i2 = e; }
        }
        float Z = 0.0f;
        for (int e = 0; e < N_EXP; ++e) {
            const float l = red[e * TOK_PER_BLOCK + lane] + b[e];
            Z += expf(l - v1);
        }
        const float p1 = 1.0f / Z;                 // exp(v1-v1)/Z
        const float p2 = expf(v2 - v1) / Z;
        const float s  = p1 + p2 + 1e-8f;

        float2* oidx  = (float2*)out;              // [16384] pairs
        float2* oprob = ((float2*)out) + T_TOKENS; // [16384] pairs
        oidx[tok]  = make_float2((float)i1, (float)i2);
        oprob[tok] = make_float2(p1 / s, p2 / s);
    }
}

extern "C" void kernel_launch(void* const* d_in, const int* in_sizes, int n_in,
                              void* d_out, int out_size, void* d_ws, size_t ws_size,
                              hipStream_t stream) {
    const float* x = (const float*)d_in[0];
    const float* W = (const float*)d_in[1];
    const float* b = (const float*)d_in[2];
    float* out = (float*)d_out;

    dim3 grid(T_TOKENS / TOK_PER_BLOCK);   // 256 blocks
    dim3 block(64 * SPLITK);               // 512 threads = 8 waves
    router_kernel<<<grid, block, 0, stream>>>(x, W, b, out);
}

// Round 2
// 988.862 us; speedup vs baseline: 3.4347x; 3.4347x over previous
//
#include <hip/hip_runtime.h>
#include <math.h>

// SimpleTTTRouter: logits = x @ W^T + b ; softmax ; top-2 ; renormalize.
// x: [16384, 4096] f32, W: [128, 4096] f32, b: [128] f32.
// out: [16384*2] indices (as float) ++ [16384*2] probs (float).
//
// R2: expert-split instead of K-split. 8 waves/block, each wave owns 16
// experts over the full K -> acc[16] fits in VGPRs (R1's acc[128] spilled
// to scratch: 8.45 GB WRITE_SIZE). lane = token; W[e][k] is wave-uniform ->
// s_load feeds v_fma_f32 (SGPR_Count=112 in R1 confirmed scalarization).
// x row streams per-lane; 8-way reuse across waves is absorbed by L1
// (live slice 64 rows x 128 B = 8 KB < 32 KB L1).

#define T_TOKENS 16384
#define D_K      4096
#define N_EXP    128
#define N_WAVES  8
#define E_PER_WAVE (N_EXP / N_WAVES)   // 16
#define TOK_PER_BLOCK 64
#define KCHUNK   4

__global__ __launch_bounds__(64 * N_WAVES, 2)
void router_kernel(const float* __restrict__ x,
                   const float* __restrict__ W,
                   const float* __restrict__ b,
                   float* __restrict__ out) {
    __shared__ float red[N_EXP * TOK_PER_BLOCK];   // [expert][token] 32 KB

    const int lane = threadIdx.x & 63;
    const int wave = __builtin_amdgcn_readfirstlane(threadIdx.x >> 6);
    const int tok  = blockIdx.x * TOK_PER_BLOCK + lane;
    const int e0   = wave * E_PER_WAVE;

    float acc[E_PER_WAVE];
#pragma unroll
    for (int ei = 0; ei < E_PER_WAVE; ++ei) acc[ei] = 0.0f;

    const float* xrow  = x + (size_t)tok * D_K;
    const float* wbase = W + (size_t)e0 * D_K;     // wave-uniform

    for (int k0 = 0; k0 < D_K; k0 += KCHUNK) {
        const float4 xv = *(const float4*)(xrow + k0);   // per-lane VMEM
#pragma unroll
        for (int ei = 0; ei < E_PER_WAVE; ++ei) {
            const float4 wv = *(const float4*)(wbase + (size_t)ei * D_K + k0); // s_load
            acc[ei] = fmaf(xv.x, wv.x, acc[ei]);
            acc[ei] = fmaf(xv.y, wv.y, acc[ei]);
            acc[ei] = fmaf(xv.z, wv.z, acc[ei]);
            acc[ei] = fmaf(xv.w, wv.w, acc[ei]);
        }
    }

    // Each wave owns a disjoint [16 x 64] slab of red -> plain stores.
    // [e][lane] layout is lane-contiguous (2 lanes/bank aliasing is free).
#pragma unroll
    for (int ei = 0; ei < E_PER_WAVE; ++ei)
        red[(e0 + ei) * TOK_PER_BLOCK + lane] = acc[ei] + b[e0 + ei];

    __syncthreads();

    if (wave == 0) {
        // lane t handles token tok: top-2 scan (jax top_k tie-break: first
        // occurrence wins via strict >), then softmax Z, then renormalize.
        float v1 = -INFINITY, v2 = -INFINITY;
        int   i1 = 0, i2 = 0;
        for (int e = 0; e < N_EXP; ++e) {
            const float l = red[e * TOK_PER_BLOCK + lane];
            if (l > v1)      { v2 = v1; i2 = i1; v1 = l; i1 = e; }
            else if (l > v2) { v2 = l; i2 = e; }
        }
        float Z = 0.0f;
        for (int e = 0; e < N_EXP; ++e) {
            const float l = red[e * TOK_PER_BLOCK + lane];
            Z += expf(l - v1);
        }
        const float p1 = 1.0f / Z;                 // exp(v1-v1)/Z
        const float p2 = expf(v2 - v1) / Z;
        const float s  = p1 + p2 + 1e-8f;

        float2* oidx  = (float2*)out;              // [16384] pairs
        float2* oprob = ((float2*)out) + T_TOKENS; // [16384] pairs
        oidx[tok]  = make_float2((float)i1, (float)i2);
        oprob[tok] = make_float2(p1 / s, p2 / s);
    }
}

extern "C" void kernel_launch(void* const* d_in, const int* in_sizes, int n_in,
                              void* d_out, int out_size, void* d_ws, size_t ws_size,
                              hipStream_t stream) {
    const float* x = (const float*)d_in[0];
    const float* W = (const float*)d_in[1];
    const float* b = (const float*)d_in[2];
    float* out = (float*)d_out;

    dim3 grid(T_TOKENS / TOK_PER_BLOCK);   // 256 blocks, ~1 per CU
    dim3 block(64 * N_WAVES);              // 512 threads = 8 waves
    router_kernel<<<grid, block, 0, stream>>>(x, W, b, out);
}

// Round 3
// 902.992 us; speedup vs baseline: 3.7614x; 1.0951x over previous
//
#include <hip/hip_runtime.h>
#include <math.h>

// SimpleTTTRouter: logits = x @ W^T + b ; softmax ; top-2 ; renormalize.
// x: [16384, 4096] f32, W: [128, 4096] f32, b: [128] f32.
// out: [16384*2] indices (as float) ++ [16384*2] probs (float).
//
// R3: LDS-staged x + 16 waves/block.
//  - R2 counters: VALUBusy 15%, FETCH 1.35 GB (5x re-fetch of x), occupancy
//    2 waves/SIMD. Per-lane global x loads had 200-900 cyc latency with no
//    hiding, and 8 drifting waves thrashed L1/L2.
//  - Fix: cooperative double-buffered LDS staging (x fetched exactly once),
//    1024-thread blocks = 16 waves = 4/SIMD, 8 experts/wave (acc[8], no
//    spill). W stays on the scalar path (wave-uniform -> s_load feeding
//    v_fma with SGPR operand).
//  - LDS row padded to 68 dwords: lane-to-lane stride 272 B = 16 B mod 128 B,
//    the same bank pattern as contiguous b128 (known near-peak). Staging
//    buffers overlaid with the logits buffer via union (dead after K-loop).

#define T_TOKENS 16384
#define D_K      4096
#define N_EXP    128
#define N_WAVES  16
#define E_PER_WAVE (N_EXP / N_WAVES)   // 8
#define TOK_PER_BLOCK 64
#define BK       64                    // k-floats per tile
#define BKP      (BK + 4)              // padded row stride (dwords)
#define NTILE    (D_K / BK)            // 64

union SMem {
    float xs[2][TOK_PER_BLOCK][BKP];   // 2 x 17408 B staging
    float red[N_EXP][TOK_PER_BLOCK];   // 32768 B logits (overlaid)
};

__global__ __launch_bounds__(64 * N_WAVES, 4)
void router_kernel(const float* __restrict__ x,
                   const float* __restrict__ W,
                   const float* __restrict__ b,
                   float* __restrict__ out) {
    __shared__ SMem sm;

    const int tid  = threadIdx.x;
    const int lane = tid & 63;
    const int wave = __builtin_amdgcn_readfirstlane(tid >> 6);
    const int tok  = blockIdx.x * TOK_PER_BLOCK + lane;
    const int e0   = wave * E_PER_WAVE;

    // staging role: thread -> (token row, 4-float chunk); 16 threads cover
    // one token's 256 B slice -> coalesced dwordx4 global reads.
    const int token_s = tid >> 4;      // 0..63
    const int jc      = tid & 15;      // 0..15
    const float* gsrc = x + (size_t)(blockIdx.x * TOK_PER_BLOCK + token_s) * D_K
                          + (size_t)jc * 4;

    // stage tile 0
    *(float4*)&sm.xs[0][token_s][jc * 4] = *(const float4*)gsrc;
    __syncthreads();

    float acc[E_PER_WAVE];
#pragma unroll
    for (int ei = 0; ei < E_PER_WAVE; ++ei) acc[ei] = 0.0f;

    const float* wbase = W + (size_t)e0 * D_K;   // wave-uniform

    for (int t = 0; t < NTILE; ++t) {
        // prefetch next tile into the other buffer (no dependency on compute)
        if (t + 1 < NTILE) {
            *(float4*)&sm.xs[(t + 1) & 1][token_s][jc * 4] =
                *(const float4*)(gsrc + (size_t)(t + 1) * BK);
        }
        const float* xb = &sm.xs[t & 1][lane][0];
        const int kt = t * BK;
#pragma unroll 4
        for (int c = 0; c < BK / 4; ++c) {
            const float4 xv = *(const float4*)(xb + c * 4);   // ds_read_b128
#pragma unroll
            for (int ei = 0; ei < E_PER_WAVE; ++ei) {
                const float4 wv = *(const float4*)(wbase + (size_t)ei * D_K
                                                   + kt + c * 4);  // s_load
                acc[ei] = fmaf(xv.x, wv.x, acc[ei]);
                acc[ei] = fmaf(xv.y, wv.y, acc[ei]);
                acc[ei] = fmaf(xv.z, wv.z, acc[ei]);
                acc[ei] = fmaf(xv.w, wv.w, acc[ei]);
            }
        }
        __syncthreads();   // buf (t+1)&1 fully written; buf t&1 fully read
    }

    // staging dead; overlay with logits buffer. Last barrier above guarantees
    // all ds_reads of xs are complete before these writes.
#pragma unroll
    for (int ei = 0; ei < E_PER_WAVE; ++ei)
        sm.red[e0 + ei][lane] = acc[ei] + b[e0 + ei];

    __syncthreads();

    if (wave == 0) {
        // lane = token: top-2 scan (strict > = jax first-occurrence
        // tie-break), then softmax Z, then renormalize.
        float v1 = -INFINITY, v2 = -INFINITY;
        int   i1 = 0, i2 = 0;
        for (int e = 0; e < N_EXP; ++e) {
            const float l = sm.red[e][lane];   // bank = lane -> conflict-free
            if (l > v1)      { v2 = v1; i2 = i1; v1 = l; i1 = e; }
            else if (l > v2) { v2 = l; i2 = e; }
        }
        float Z = 0.0f;
        for (int e = 0; e < N_EXP; ++e)
            Z += expf(sm.red[e][lane] - v1);

        const float p1 = 1.0f / Z;
        const float p2 = expf(v2 - v1) / Z;
        const float s  = p1 + p2 + 1e-8f;

        float2* oidx  = (float2*)out;              // [16384] index pairs
        float2* oprob = ((float2*)out) + T_TOKENS; // [16384] prob pairs
        oidx[tok]  = make_float2((float)i1, (float)i2);
        oprob[tok] = make_float2(p1 / s, p2 / s);
    }
}

extern "C" void kernel_launch(void* const* d_in, const int* in_sizes, int n_in,
                              void* d_out, int out_size, void* d_ws, size_t ws_size,
                              hipStream_t stream) {
    const float* x = (const float*)d_in[0];
    const float* W = (const float*)d_in[1];
    const float* b = (const float*)d_in[2];
    float* out = (float*)d_out;

    dim3 grid(T_TOKENS / TOK_PER_BLOCK);   // 256 blocks, 1/CU
    dim3 block(64 * N_WAVES);              // 1024 threads = 16 waves
    router_kernel<<<grid, block, 0, stream>>>(x, W, b, out);
}

// Round 4
// 777.567 us; speedup vs baseline: 4.3681x; 1.1613x over previous
//
#include <hip/hip_runtime.h>
#include <math.h>

// SimpleTTTRouter: logits = x @ W^T + b ; softmax ; top-2 ; renormalize.
// x: [16384, 4096] f32, W: [128, 4096] f32, b: [128] f32.
// out: [16384*2] indices (as float) ++ [16384*2] probs (float).
//
// R4: attack the scalar-feed + single-block-per-CU limits seen in R3
// (VALUBusy 38%, occupancy 47%, FETCH already ~ideal):
//  - Split-K=2 across blocks: grid 512 -> 2 blocks/CU -> 8 waves/SIMD;
//    barrier/lgkm stalls of one block overlap the other's compute.
//  - Each wave owns 8 experts x half-K: acc[8] is a final partial sum ->
//    stored directly to ws[kh][e][tok] (coalesced); no LDS reduction.
//  - W loads widened to 8 consecutive floats per expert per chunk ->
//    s_load_dwordx8 (merged), scalar issue 1.0 -> 0.25 per cyc per CU.
//  - Finalize kernel: logit = part0 + part1 + b[e]; top-2 (strict-> scan,
//    jax first-occurrence tie-break); softmax Z; renormalize with +1e-8.
// Workspace: 2 * 128 * 16384 * 4 B = 16 MB.

#define T_TOKENS 16384
#define D_K      4096
#define N_EXP    128
#define N_WAVES  16
#define E_PER_WAVE (N_EXP / N_WAVES)   // 8
#define TOK_PER_BLOCK 64
#define KSPLIT   2
#define KHALF    (D_K / KSPLIT)        // 2048
#define BK       64                    // k-floats per LDS tile
#define BKP      (BK + 4)              // padded row stride (dwords)
#define NTILE    (KHALF / BK)          // 32

__global__ __launch_bounds__(64 * N_WAVES, 8)
void router_partial(const float* __restrict__ x,
                    const float* __restrict__ W,
                    float* __restrict__ part) {
    __shared__ float xs[2][TOK_PER_BLOCK][BKP];   // 34816 B

    const int tid  = threadIdx.x;
    const int lane = tid & 63;
    const int wave = __builtin_amdgcn_readfirstlane(tid >> 6);
    const int g    = blockIdx.x;       // token group 0..255
    const int kh   = blockIdx.y;       // K half 0..1
    const int e0   = wave * E_PER_WAVE;
    const int tok  = g * TOK_PER_BLOCK + lane;

    // staging role: 16 threads cover one token's 64-float slice (float4 each)
    const int token_s = tid >> 4;      // 0..63
    const int jc      = tid & 15;      // 0..15
    const float* gsrc = x + (size_t)(g * TOK_PER_BLOCK + token_s) * D_K
                          + (size_t)kh * KHALF + (size_t)jc * 4;

    *(float4*)&xs[0][token_s][jc * 4] = *(const float4*)gsrc;   // tile 0

    float acc[E_PER_WAVE];
#pragma unroll
    for (int ei = 0; ei < E_PER_WAVE; ++ei) acc[ei] = 0.0f;

    // per-expert W row pointers (wave-uniform -> SGPR pairs, imm k-offsets)
    const float* wrow[E_PER_WAVE];
#pragma unroll
    for (int ei = 0; ei < E_PER_WAVE; ++ei)
        wrow[ei] = W + (size_t)(e0 + ei) * D_K + (size_t)kh * KHALF;

    __syncthreads();

    for (int t = 0; t < NTILE; ++t) {
        if (t + 1 < NTILE) {
            *(float4*)&xs[(t + 1) & 1][token_s][jc * 4] =
                *(const float4*)(gsrc + (size_t)(t + 1) * BK);
        }
        const float* xb = &xs[t & 1][lane][0];
        const int kt = t * BK;
#pragma unroll
        for (int c = 0; c < BK / 8; ++c) {
            const float4 xa = *(const float4*)(xb + c * 8);       // ds_read_b128
            const float4 xbv = *(const float4*)(xb + c * 8 + 4);  // ds_read_b128
#pragma unroll
            for (int ei = 0; ei < E_PER_WAVE; ++ei) {
                const float* wp = wrow[ei] + kt + c * 8;
                const float4 w0 = *(const float4*)(wp);       // merge ->
                const float4 w1 = *(const float4*)(wp + 4);   // s_load_dwordx8
                acc[ei] = fmaf(xa.x,  w0.x, acc[ei]);
                acc[ei] = fmaf(xa.y,  w0.y, acc[ei]);
                acc[ei] = fmaf(xa.z,  w0.z, acc[ei]);
                acc[ei] = fmaf(xa.w,  w0.w, acc[ei]);
                acc[ei] = fmaf(xbv.x, w1.x, acc[ei]);
                acc[ei] = fmaf(xbv.y, w1.y, acc[ei]);
                acc[ei] = fmaf(xbv.z, w1.z, acc[ei]);
                acc[ei] = fmaf(xbv.w, w1.w, acc[ei]);
            }
        }
        __syncthreads();
    }

    // part[kh][e][tok]: lane-contiguous -> coalesced b32 stores
    float* pbase = part + ((size_t)kh * N_EXP + e0) * T_TOKENS + tok;
#pragma unroll
    for (int ei = 0; ei < E_PER_WAVE; ++ei)
        pbase[(size_t)ei * T_TOKENS] = acc[ei];
}

__global__ __launch_bounds__(256)
void router_finalize(const float* __restrict__ part,
                     const float* __restrict__ b,
                     float* __restrict__ out) {
    const int tok = blockIdx.x * 256 + threadIdx.x;
    const float* p0 = part + tok;                          // [e][tok], kh=0
    const float* p1 = part + (size_t)N_EXP * T_TOKENS + tok;

    float v1 = -INFINITY, v2 = -INFINITY;
    int   i1 = 0, i2 = 0;
    float lg[N_EXP];
#pragma unroll 8
    for (int e = 0; e < N_EXP; ++e) {
        const float l = p0[(size_t)e * T_TOKENS] + p1[(size_t)e * T_TOKENS] + b[e];
        lg[e] = l;
        if (l > v1)      { v2 = v1; i2 = i1; v1 = l; i1 = e; }
        else if (l > v2) { v2 = l; i2 = e; }
    }
    float Z = 0.0f;
#pragma unroll 8
    for (int e = 0; e < N_EXP; ++e) Z += expf(lg[e] - v1);

    const float p1v = 1.0f / Z;
    const float p2v = expf(v2 - v1) / Z;
    const float s   = p1v + p2v + 1e-8f;

    float2* oidx  = (float2*)out;              // [16384] index pairs
    float2* oprob = ((float2*)out) + T_TOKENS; // [16384] prob pairs
    oidx[tok]  = make_float2((float)i1, (float)i2);
    oprob[tok] = make_float2(p1v / s, p2v / s);
}

extern "C" void kernel_launch(void* const* d_in, const int* in_sizes, int n_in,
                              void* d_out, int out_size, void* d_ws, size_t ws_size,
                              hipStream_t stream) {
    const float* x = (const float*)d_in[0];
    const float* W = (const float*)d_in[1];
    const float* b = (const float*)d_in[2];
    float* out  = (float*)d_out;
    float* part = (float*)d_ws;   // needs 2*128*16384*4 = 16 MB

    dim3 grid(T_TOKENS / TOK_PER_BLOCK, KSPLIT);   // 256 x 2 = 512 blocks
    dim3 block(64 * N_WAVES);                      // 1024 threads = 16 waves
    router_partial<<<grid, block, 0, stream>>>(x, W, part);

    router_finalize<<<dim3(T_TOKENS / 256), dim3(256), 0, stream>>>(part, b, out);
}